// Round 3
// baseline (982.820 us; speedup 1.0000x reference)
//
#include <hip/hip_runtime.h>
#include <hip/hip_bf16.h>
#include <cstdint>

// TGAT fused pipeline for MI355X.
// Stages:
//   k1: h1pre = x @ Wlin + blin                       [N,32]
//   k2: node encoders + gated combine + Q/K/V/skip    [N,32] x4
//   k3: edge kernel — edge feature matvec, attention  (one pass; softmax
//       folded: accumulate exp(alpha)*msg and exp(alpha) via atomics)
//   k4: normalize + skip + @Wout + log_softmax        [N,2]
//
// Workspace layout (floats): h1pre | q | k | v | skip | agg | denom
//   = 6*N*32 + 2*N floats ≈ 77.6 MB for N=100k.

#define FIN 172
#define HID 32
#define HC 32          // heads*channels
#define INV_SQRT_C 0.25f

// ---------------------------------------------------------------------------
// k1: h1pre = x @ Wlin + blin.  Block = 256 threads = 8 rows x 32 out-cols.
// Wlin transposed into LDS (padded to 174 floats/row for bank spread),
// x rows staged in LDS, float2 inner loop.
// ---------------------------------------------------------------------------
__global__ __launch_bounds__(256) void k1_lin(
    const float* __restrict__ x, const float* __restrict__ Wlin,
    const float* __restrict__ blin, float* __restrict__ h1pre, int n)
{
    __shared__ __align__(16) float WlT[32][174];   // [out][k], padded
    __shared__ __align__(16) float xs[8][FIN];
    const int t = threadIdx.x;

    for (int i = t; i < FIN * 32; i += 256) {
        int kk = i >> 5, o = i & 31;               // Wlin row-major [k][o]
        WlT[o][kk] = Wlin[i];
    }
    const int row0 = blockIdx.x * 8;
    for (int i = t; i < 8 * FIN; i += 256) {
        int rr = i / FIN, kk = i - rr * FIN;
        int gr = row0 + rr;
        xs[rr][kk] = (gr < n) ? x[(size_t)gr * FIN + kk] : 0.f;
    }
    __syncthreads();

    const int o = t & 31, r = t >> 5;
    float acc = blin[o];
    const float2* wp = reinterpret_cast<const float2*>(&WlT[o][0]);
    const float2* xp = reinterpret_cast<const float2*>(&xs[r][0]);
    #pragma unroll 4
    for (int kk = 0; kk < FIN / 2; ++kk) {
        float2 wv = wp[kk], xv = xp[kk];
        acc = fmaf(xv.x, wv.x, acc);
        acc = fmaf(xv.y, wv.y, acc);
    }
    const int gr = row0 + r;
    if (gr < n) h1pre[(size_t)gr * 32 + o] = acc;
}

// ---------------------------------------------------------------------------
// Small matvec helper: out[o] = B[o] + sum_k v[k] * W[k*O + o].
// W/B live in LDS (wave-uniform broadcast reads, float4 where possible).
// ---------------------------------------------------------------------------
template <int K, int O>
__device__ __forceinline__ void matvecKO(const float* __restrict__ v,
                                         const float* __restrict__ W,
                                         const float* __restrict__ B,
                                         float* __restrict__ out)
{
    #pragma unroll
    for (int o4 = 0; o4 < O / 4; ++o4) {
        float a0 = B[o4 * 4 + 0], a1 = B[o4 * 4 + 1];
        float a2 = B[o4 * 4 + 2], a3 = B[o4 * 4 + 3];
        #pragma unroll
        for (int k = 0; k < K; ++k) {
            float4 wv = *reinterpret_cast<const float4*>(&W[k * O + o4 * 4]);
            float hv = v[k];
            a0 = fmaf(hv, wv.x, a0);
            a1 = fmaf(hv, wv.y, a1);
            a2 = fmaf(hv, wv.z, a2);
            a3 = fmaf(hv, wv.w, a3);
        }
        out[o4 * 4 + 0] = a0; out[o4 * 4 + 1] = a1;
        out[o4 * 4 + 2] = a2; out[o4 * 4 + 3] = a3;
    }
}

__device__ __forceinline__ void store32(float* __restrict__ dst,
                                        const float* __restrict__ v)
{
    float4* d4 = reinterpret_cast<float4*>(dst);
    #pragma unroll
    for (int i = 0; i < 8; ++i)
        d4[i] = make_float4(v[4 * i], v[4 * i + 1], v[4 * i + 2], v[4 * i + 3]);
}

// ---------------------------------------------------------------------------
// k2: per-node encoder + combine + projections. One thread per node.
// ---------------------------------------------------------------------------
__global__ __launch_bounds__(256) void k2_enc(
    const float* __restrict__ h1pre,
    const float* __restrict__ node_interval, const float* __restrict__ node_degree,
    const float* __restrict__ Wtf, const float* __restrict__ btf,
    const float* __restrict__ Wd,  const float* __restrict__ bd,
    const float* __restrict__ Wenc, const float* __restrict__ benc,
    const float* __restrict__ Wx,  const float* __restrict__ bx,
    const float* __restrict__ Wcomb, const float* __restrict__ bcomb,
    const float* __restrict__ Wq,  const float* __restrict__ bq,
    const float* __restrict__ Wk,  const float* __restrict__ bk,
    const float* __restrict__ Wv,  const float* __restrict__ bv,
    const float* __restrict__ Wskip, const float* __restrict__ bskip,
    float* __restrict__ qb, float* __restrict__ kb, float* __restrict__ vb,
    float* __restrict__ skipb, int n)
{
    __shared__ __align__(16) float sWenc[64], sWx[256], sWcomb[1280];
    __shared__ __align__(16) float sWq[1024], sWk[1024], sWv[1024], sWs[1024];
    __shared__ float sWtf[8], sbtf[8], sWd[8], sbd[8], sbenc[8], sbx[8];
    __shared__ float sbcomb[32], sbq[32], sbk[32], sbv[32], sbs[32];

    const int t = threadIdx.x;
    if (t < 8) {
        sWtf[t] = Wtf[t]; sbtf[t] = btf[t];
        sWd[t]  = Wd[t];  sbd[t]  = bd[t];
        sbenc[t] = benc[t]; sbx[t] = bx[t];
    }
    if (t < 32) {
        sbcomb[t] = bcomb[t]; sbq[t] = bq[t]; sbk[t] = bk[t];
        sbv[t] = bv[t]; sbs[t] = bskip[t];
    }
    if (t < 64) sWenc[t] = Wenc[t];
    if (t < 256) sWx[t] = Wx[t];
    for (int i = t; i < 1280; i += 256) sWcomb[i] = Wcomb[i];
    for (int i = t; i < 1024; i += 256) {
        sWq[i] = Wq[i]; sWk[i] = Wk[i]; sWv[i] = Wv[i]; sWs[i] = Wskip[i];
    }
    __syncthreads();

    const int nid = blockIdx.x * 256 + t;
    if (nid >= n) return;

    float h1p[32];
    {
        const float2* hp = reinterpret_cast<const float2*>(h1pre + (size_t)nid * 32);
        #pragma unroll
        for (int i = 0; i < 16; ++i) {
            float2 v2 = hp[i];
            h1p[2 * i] = v2.x; h1p[2 * i + 1] = v2.y;
        }
    }
    const float ti = node_interval[nid], dg = node_degree[nid];
    float tf[8], de[8];
    #pragma unroll
    for (int j = 0; j < 8; ++j) {
        tf[j] = fmaf(ti, sWtf[j], sbtf[j]);
        de[j] = fmaf(dg, sWd[j], sbd[j]);
    }
    // x_proj = tanh(h1p @ Wx + bx)
    float xp[8];
    matvecKO<32, 8>(h1p, sWx, sbx, xp);
    #pragma unroll
    for (int o = 0; o < 8; ++o) xp[o] = tanhf(xp[o]);

    // scores: tanh(enc @ Wenc + benc) . x_proj, per k in {tf, de}
    float ep0[8], ep1[8];
    matvecKO<8, 8>(tf, sWenc, sbenc, ep0);
    matvecKO<8, 8>(de, sWenc, sbenc, ep1);
    float sc0 = 0.f, sc1 = 0.f;
    #pragma unroll
    for (int o = 0; o < 8; ++o) {
        sc0 = fmaf(tanhf(ep0[o]), xp[o], sc0);
        sc1 = fmaf(tanhf(ep1[o]), xp[o], sc1);
    }
    const float mm = fmaxf(sc0, sc1);
    const float e0 = __expf(sc0 - mm), e1 = __expf(sc1 - mm);
    const float inv = 1.f / (e0 + e1);
    const float s0 = e0 * inv, s1 = e1 * inv;

    // combine: [h1p | context] @ Wcomb + bcomb
    float v40[40];
    #pragma unroll
    for (int i = 0; i < 32; ++i) v40[i] = h1p[i];
    #pragma unroll
    for (int j = 0; j < 8; ++j) v40[32 + j] = fmaf(s0, tf[j], s1 * de[j]);
    float h1[32];
    matvecKO<40, 32>(v40, sWcomb, sbcomb, h1);

    // projections
    float tmp[32];
    matvecKO<32, 32>(h1, sWq, sbq, tmp); store32(qb   + (size_t)nid * 32, tmp);
    matvecKO<32, 32>(h1, sWk, sbk, tmp); store32(kb   + (size_t)nid * 32, tmp);
    matvecKO<32, 32>(h1, sWv, sbv, tmp); store32(vb   + (size_t)nid * 32, tmp);
    matvecKO<32, 32>(h1, sWs, sbs, tmp); store32(skipb + (size_t)nid * 32, tmp);
}

// ---------------------------------------------------------------------------
// k3: edge kernel. 32 lanes per edge (lane = flat channel c = h*16+cc),
// 8 edges per 256-thread block. Single pass: accumulate exp(alpha)*(v+e)
// and exp(alpha) via atomics; normalization deferred to k4 (softmax is
// shift-invariant; alpha is O(0.1) so no max subtraction needed).
// ---------------------------------------------------------------------------
__global__ __launch_bounds__(256) void k3_edge(
    const int* __restrict__ ei, const float* __restrict__ node_time,
    const float* __restrict__ edge_time,
    const float* __restrict__ qb, const float* __restrict__ kb,
    const float* __restrict__ vb,
    const float* __restrict__ Wt, const float* __restrict__ bt,
    const float* __restrict__ We, const float* __restrict__ be,
    float* __restrict__ agg, float* __restrict__ den, int numE)
{
    __shared__ float2 sWtb[32];
    __shared__ float sWe[1024];
    __shared__ float sbe[32];
    const int t = threadIdx.x;
    if (t < 32) { sWtb[t] = make_float2(Wt[t], bt[t]); sbe[t] = be[t]; }
    for (int i = t; i < 1024; i += 256) sWe[i] = We[i];
    __syncthreads();

    const int c = t & 31;
    const int eidx = blockIdx.x * 8 + (t >> 5);
    if (eidx >= numE) return;

    const int src = ei[eidx];
    const int dst = ei[numE + eidx];
    const float rel = node_time[src] - edge_time[eidx];

    // e[c] = be[c] + sum_j cos(rel*Wt[j]+bt[j]) * We[j][c]
    float ef = sbe[c];
    #pragma unroll
    for (int j = 0; j < 32; ++j) {
        float2 wb = sWtb[j];
        float ct = __cosf(fmaf(rel, wb.x, wb.y));
        ef = fmaf(ct, sWe[j * 32 + c], ef);
    }

    const float qd = qb[(size_t)dst * 32 + c];
    const float ks = kb[(size_t)src * 32 + c];
    const float vs = vb[(size_t)src * 32 + c];

    // alpha_h = sum_{cc<16} q[dst,h,cc]*(k[src,h,cc]+e[h,cc]) * 0.25
    float part = qd * (ks + ef);
    part += __shfl_xor(part, 1);
    part += __shfl_xor(part, 2);
    part += __shfl_xor(part, 4);
    part += __shfl_xor(part, 8);
    const float w = __expf(part * INV_SQRT_C);

    if ((c & 15) == 0) atomicAdd(&den[(size_t)dst * 2 + (c >> 4)], w);
    atomicAdd(&agg[(size_t)dst * 32 + c], w * (vs + ef));
}

// ---------------------------------------------------------------------------
// k4: h2 = agg/denom + skip; out = log_softmax(h2 @ Wout + bout).
// ---------------------------------------------------------------------------
__global__ __launch_bounds__(256) void k4_out(
    const float* __restrict__ agg, const float* __restrict__ den,
    const float* __restrict__ skipb,
    const float* __restrict__ Wout, const float* __restrict__ bout,
    float* __restrict__ out, int n)
{
    __shared__ float sW[64];
    __shared__ float sb[2];
    const int t = threadIdx.x;
    if (t < 64) sW[t] = Wout[t];
    if (t < 2) sb[t] = bout[t];
    __syncthreads();

    const int nid = blockIdx.x * 256 + t;
    if (nid >= n) return;

    const float inv0 = 1.f / (den[(size_t)nid * 2 + 0] + 1e-16f);
    const float inv1 = 1.f / (den[(size_t)nid * 2 + 1] + 1e-16f);
    const float4* ag4 = reinterpret_cast<const float4*>(agg + (size_t)nid * 32);
    const float4* sk4 = reinterpret_cast<const float4*>(skipb + (size_t)nid * 32);

    float o0 = sb[0], o1 = sb[1];
    #pragma unroll
    for (int c4 = 0; c4 < 8; ++c4) {
        float4 a = ag4[c4], s = sk4[c4];
        const float iv = (c4 < 4) ? inv0 : inv1;
        float h;
        h = fmaf(a.x, iv, s.x); o0 = fmaf(h, sW[(c4 * 4 + 0) * 2], o0); o1 = fmaf(h, sW[(c4 * 4 + 0) * 2 + 1], o1);
        h = fmaf(a.y, iv, s.y); o0 = fmaf(h, sW[(c4 * 4 + 1) * 2], o0); o1 = fmaf(h, sW[(c4 * 4 + 1) * 2 + 1], o1);
        h = fmaf(a.z, iv, s.z); o0 = fmaf(h, sW[(c4 * 4 + 2) * 2], o0); o1 = fmaf(h, sW[(c4 * 4 + 2) * 2 + 1], o1);
        h = fmaf(a.w, iv, s.w); o0 = fmaf(h, sW[(c4 * 4 + 3) * 2], o0); o1 = fmaf(h, sW[(c4 * 4 + 3) * 2 + 1], o1);
    }
    const float mm = fmaxf(o0, o1);
    const float lse = mm + __logf(__expf(o0 - mm) + __expf(o1 - mm));
    out[(size_t)nid * 2 + 0] = o0 - lse;
    out[(size_t)nid * 2 + 1] = o1 - lse;
}

// ---------------------------------------------------------------------------
extern "C" void kernel_launch(void* const* d_in, const int* in_sizes, int n_in,
                              void* d_out, int out_size, void* d_ws, size_t ws_size,
                              hipStream_t stream)
{
    const float* x             = (const float*)d_in[0];
    const int*   ei            = (const int*)  d_in[1];
    const float* node_time     = (const float*)d_in[2];
    const float* edge_time     = (const float*)d_in[3];
    const float* node_interval = (const float*)d_in[4];
    const float* node_degree   = (const float*)d_in[5];
    const float* Wt    = (const float*)d_in[6];  const float* bt    = (const float*)d_in[7];
    const float* Wd    = (const float*)d_in[8];  const float* bd    = (const float*)d_in[9];
    const float* Wtf   = (const float*)d_in[10]; const float* btf   = (const float*)d_in[11];
    const float* Wenc  = (const float*)d_in[12]; const float* benc  = (const float*)d_in[13];
    const float* Wx    = (const float*)d_in[14]; const float* bx    = (const float*)d_in[15];
    const float* Wlin  = (const float*)d_in[16]; const float* blin  = (const float*)d_in[17];
    const float* Wcomb = (const float*)d_in[18]; const float* bcomb = (const float*)d_in[19];
    const float* Wq    = (const float*)d_in[20]; const float* bq    = (const float*)d_in[21];
    const float* Wk    = (const float*)d_in[22]; const float* bk    = (const float*)d_in[23];
    const float* Wv    = (const float*)d_in[24]; const float* bv    = (const float*)d_in[25];
    const float* We    = (const float*)d_in[26]; const float* be    = (const float*)d_in[27];
    const float* Wskip = (const float*)d_in[28]; const float* bskip = (const float*)d_in[29];
    const float* Wout  = (const float*)d_in[30]; const float* bout  = (const float*)d_in[31];

    const int n    = in_sizes[2];   // node_time: [N]
    const int numE = in_sizes[3];   // edge_time: [E,1]

    float* ws    = (float*)d_ws;
    float* h1pre = ws;  ws += (size_t)n * 32;
    float* qb    = ws;  ws += (size_t)n * 32;
    float* kb    = ws;  ws += (size_t)n * 32;
    float* vb    = ws;  ws += (size_t)n * 32;
    float* skipb = ws;  ws += (size_t)n * 32;
    float* agg   = ws;  ws += (size_t)n * 32;
    float* den   = ws;  ws += (size_t)n * 2;
    // total: 6*N*32 + 2*N floats (~77.6 MB) — fits typical d_ws

    // zero the atomic accumulators (agg and den are contiguous)
    hipMemsetAsync(agg, 0, (size_t)n * 34 * sizeof(float), stream);

    k1_lin<<<(n + 7) / 8, 256, 0, stream>>>(x, Wlin, blin, h1pre, n);

    k2_enc<<<(n + 255) / 256, 256, 0, stream>>>(
        h1pre, node_interval, node_degree,
        Wtf, btf, Wd, bd, Wenc, benc, Wx, bx, Wcomb, bcomb,
        Wq, bq, Wk, bk, Wv, bv, Wskip, bskip,
        qb, kb, vb, skipb, n);

    k3_edge<<<(numE + 7) / 8, 256, 0, stream>>>(
        ei, node_time, edge_time, qb, kb, vb,
        Wt, bt, We, be, agg, den, numE);

    k4_out<<<(n + 255) / 256, 256, 0, stream>>>(
        agg, den, skipb, Wout, bout, (float*)d_out, n);
}

// Round 4
// 673.845 us; speedup vs baseline: 1.4585x; 1.4585x over previous
//
#include <hip/hip_runtime.h>
#include <hip/hip_bf16.h>
#include <cstdint>

// TGAT fused pipeline for MI355X.
// Stages:
//   k1: h1pre = x @ Wlin + blin                       [N,32]
//   k2: node encoders + gated combine + Q/K/V/skip    [N,32] x4
//   k3: edge kernel — MFMA edge-feature matvec + attention, one pass
//       (softmax folded: accumulate exp(alpha)*msg and exp(alpha) via atomics)
//   k4: normalize + skip + @Wout + log_softmax        [N,2]

#define FIN 172
#define HID 32
#define INV_SQRT_C 0.25f

typedef _Float16 f16x8 __attribute__((ext_vector_type(8)));
typedef float f32x4 __attribute__((ext_vector_type(4)));

// ---------------------------------------------------------------------------
// k1: h1pre = x @ Wlin + blin.  Block = 256 threads = 8 rows x 32 out-cols.
// ---------------------------------------------------------------------------
__global__ __launch_bounds__(256) void k1_lin(
    const float* __restrict__ x, const float* __restrict__ Wlin,
    const float* __restrict__ blin, float* __restrict__ h1pre, int n)
{
    __shared__ __align__(16) float WlT[32][174];   // [out][k], padded
    __shared__ __align__(16) float xs[8][FIN];
    const int t = threadIdx.x;

    for (int i = t; i < FIN * 32; i += 256) {
        int kk = i >> 5, o = i & 31;               // Wlin row-major [k][o]
        WlT[o][kk] = Wlin[i];
    }
    const int row0 = blockIdx.x * 8;
    for (int i = t; i < 8 * FIN; i += 256) {
        int rr = i / FIN, kk = i - rr * FIN;
        int gr = row0 + rr;
        xs[rr][kk] = (gr < n) ? x[(size_t)gr * FIN + kk] : 0.f;
    }
    __syncthreads();

    const int o = t & 31, r = t >> 5;
    float acc = blin[o];
    const float2* wp = reinterpret_cast<const float2*>(&WlT[o][0]);
    const float2* xp = reinterpret_cast<const float2*>(&xs[r][0]);
    #pragma unroll 4
    for (int kk = 0; kk < FIN / 2; ++kk) {
        float2 wv = wp[kk], xv = xp[kk];
        acc = fmaf(xv.x, wv.x, acc);
        acc = fmaf(xv.y, wv.y, acc);
    }
    const int gr = row0 + r;
    if (gr < n) h1pre[(size_t)gr * 32 + o] = acc;
}

// ---------------------------------------------------------------------------
// Small matvec helper: out[o] = B[o] + sum_k v[k] * W[k*O + o]. W/B in LDS.
// ---------------------------------------------------------------------------
template <int K, int O>
__device__ __forceinline__ void matvecKO(const float* __restrict__ v,
                                         const float* __restrict__ W,
                                         const float* __restrict__ B,
                                         float* __restrict__ out)
{
    #pragma unroll
    for (int o4 = 0; o4 < O / 4; ++o4) {
        float a0 = B[o4 * 4 + 0], a1 = B[o4 * 4 + 1];
        float a2 = B[o4 * 4 + 2], a3 = B[o4 * 4 + 3];
        #pragma unroll
        for (int k = 0; k < K; ++k) {
            float4 wv = *reinterpret_cast<const float4*>(&W[k * O + o4 * 4]);
            float hv = v[k];
            a0 = fmaf(hv, wv.x, a0);
            a1 = fmaf(hv, wv.y, a1);
            a2 = fmaf(hv, wv.z, a2);
            a3 = fmaf(hv, wv.w, a3);
        }
        out[o4 * 4 + 0] = a0; out[o4 * 4 + 1] = a1;
        out[o4 * 4 + 2] = a2; out[o4 * 4 + 3] = a3;
    }
}

__device__ __forceinline__ void store32(float* __restrict__ dst,
                                        const float* __restrict__ v)
{
    float4* d4 = reinterpret_cast<float4*>(dst);
    #pragma unroll
    for (int i = 0; i < 8; ++i)
        d4[i] = make_float4(v[4 * i], v[4 * i + 1], v[4 * i + 2], v[4 * i + 3]);
}

// ---------------------------------------------------------------------------
// k2: per-node encoder + combine + projections. One thread per node.
// ---------------------------------------------------------------------------
__global__ __launch_bounds__(256) void k2_enc(
    const float* __restrict__ h1pre,
    const float* __restrict__ node_interval, const float* __restrict__ node_degree,
    const float* __restrict__ Wtf, const float* __restrict__ btf,
    const float* __restrict__ Wd,  const float* __restrict__ bd,
    const float* __restrict__ Wenc, const float* __restrict__ benc,
    const float* __restrict__ Wx,  const float* __restrict__ bx,
    const float* __restrict__ Wcomb, const float* __restrict__ bcomb,
    const float* __restrict__ Wq,  const float* __restrict__ bq,
    const float* __restrict__ Wk,  const float* __restrict__ bk,
    const float* __restrict__ Wv,  const float* __restrict__ bv,
    const float* __restrict__ Wskip, const float* __restrict__ bskip,
    float* __restrict__ qb, float* __restrict__ kb, float* __restrict__ vb,
    float* __restrict__ skipb, int n)
{
    __shared__ __align__(16) float sWenc[64], sWx[256], sWcomb[1280];
    __shared__ __align__(16) float sWq[1024], sWk[1024], sWv[1024], sWs[1024];
    __shared__ float sWtf[8], sbtf[8], sWd[8], sbd[8], sbenc[8], sbx[8];
    __shared__ float sbcomb[32], sbq[32], sbk[32], sbv[32], sbs[32];

    const int t = threadIdx.x;
    if (t < 8) {
        sWtf[t] = Wtf[t]; sbtf[t] = btf[t];
        sWd[t]  = Wd[t];  sbd[t]  = bd[t];
        sbenc[t] = benc[t]; sbx[t] = bx[t];
    }
    if (t < 32) {
        sbcomb[t] = bcomb[t]; sbq[t] = bq[t]; sbk[t] = bk[t];
        sbv[t] = bv[t]; sbs[t] = bskip[t];
    }
    if (t < 64) sWenc[t] = Wenc[t];
    if (t < 256) sWx[t] = Wx[t];
    for (int i = t; i < 1280; i += 256) sWcomb[i] = Wcomb[i];
    for (int i = t; i < 1024; i += 256) {
        sWq[i] = Wq[i]; sWk[i] = Wk[i]; sWv[i] = Wv[i]; sWs[i] = Wskip[i];
    }
    __syncthreads();

    const int nid = blockIdx.x * 256 + t;
    if (nid >= n) return;

    float h1p[32];
    {
        const float2* hp = reinterpret_cast<const float2*>(h1pre + (size_t)nid * 32);
        #pragma unroll
        for (int i = 0; i < 16; ++i) {
            float2 v2 = hp[i];
            h1p[2 * i] = v2.x; h1p[2 * i + 1] = v2.y;
        }
    }
    const float ti = node_interval[nid], dg = node_degree[nid];
    float tf[8], de[8];
    #pragma unroll
    for (int j = 0; j < 8; ++j) {
        tf[j] = fmaf(ti, sWtf[j], sbtf[j]);
        de[j] = fmaf(dg, sWd[j], sbd[j]);
    }
    float xp[8];
    matvecKO<32, 8>(h1p, sWx, sbx, xp);
    #pragma unroll
    for (int o = 0; o < 8; ++o) xp[o] = tanhf(xp[o]);

    float ep0[8], ep1[8];
    matvecKO<8, 8>(tf, sWenc, sbenc, ep0);
    matvecKO<8, 8>(de, sWenc, sbenc, ep1);
    float sc0 = 0.f, sc1 = 0.f;
    #pragma unroll
    for (int o = 0; o < 8; ++o) {
        sc0 = fmaf(tanhf(ep0[o]), xp[o], sc0);
        sc1 = fmaf(tanhf(ep1[o]), xp[o], sc1);
    }
    const float mm = fmaxf(sc0, sc1);
    const float e0 = __expf(sc0 - mm), e1 = __expf(sc1 - mm);
    const float inv = 1.f / (e0 + e1);
    const float s0 = e0 * inv, s1 = e1 * inv;

    float v40[40];
    #pragma unroll
    for (int i = 0; i < 32; ++i) v40[i] = h1p[i];
    #pragma unroll
    for (int j = 0; j < 8; ++j) v40[32 + j] = fmaf(s0, tf[j], s1 * de[j]);
    float h1[32];
    matvecKO<40, 32>(v40, sWcomb, sbcomb, h1);

    float tmp[32];
    matvecKO<32, 32>(h1, sWq, sbq, tmp); store32(qb   + (size_t)nid * 32, tmp);
    matvecKO<32, 32>(h1, sWk, sbk, tmp); store32(kb   + (size_t)nid * 32, tmp);
    matvecKO<32, 32>(h1, sWv, sbv, tmp); store32(vb   + (size_t)nid * 32, tmp);
    matvecKO<32, 32>(h1, sWs, sbs, tmp); store32(skipb + (size_t)nid * 32, tmp);
}

// ---------------------------------------------------------------------------
// k3: edge kernel, MFMA edition. One wave = one 16-edge tile (grid-stride).
//
// ef[e][c] = be[c] + sum_j cos(rel_e*Wt[j]+bt[j]) * We[j][c] is computed as
// a 16x32 @ 32x32 matmul via two mfma_f32_16x16x32_f16 (head-0 cols, head-1
// cols). Fragment maps (A row = lane&15, k = 8*(lane>>4)+i; B col = lane&15,
// same k map; C col = lane&15, row = 4*(lane>>4)+reg — m89-verified). Any
// discrepancy in the within-group k order cancels: A and B use the same map
// and sum_k is permutation-invariant.
//
// After MFMA, lane (g,m) holds ef for edges e0+4g+r (r=0..3) at channels m
// (head 0) and 16+m (head 1). Attention dot reduces over the 16 lanes of the
// group via shfl_xor; exp(alpha)*msg and exp(alpha) accumulate via atomics
// (softmax normalization deferred to k4 — shift-invariant, alpha is O(0.1)).
//
// We/Wt/bt/be live in registers, loaded once per thread (persistent waves).
// Zero LDS. Each cos is computed exactly once per edge (vs 32x in round 2).
// ---------------------------------------------------------------------------
__global__ __launch_bounds__(256) void k3_edge(
    const int* __restrict__ ei, const float* __restrict__ node_time,
    const float* __restrict__ edge_time,
    const float* __restrict__ qb, const float* __restrict__ kb,
    const float* __restrict__ vb,
    const float* __restrict__ Wt, const float* __restrict__ bt,
    const float* __restrict__ We, const float* __restrict__ be,
    float* __restrict__ agg, float* __restrict__ den,
    int numE, int nTiles)
{
    const int lane = threadIdx.x & 63;
    const int g = lane >> 4;          // k-group / edge-row group
    const int m = lane & 15;          // A row (edge-in-tile) / B,C column

    // Per-thread constants (amortized over the grid-stride loop).
    float wtr[8], btr[8];
    f16x8 B0, B1;
    #pragma unroll
    for (int i = 0; i < 8; ++i) {
        const int k = g * 8 + i;
        wtr[i] = Wt[k];
        btr[i] = bt[k];
        B0[i] = (_Float16)We[k * 32 + m];
        B1[i] = (_Float16)We[k * 32 + 16 + m];
    }
    const float be0 = be[m], be1 = be[16 + m];

    const int wid    = blockIdx.x * (blockDim.x >> 6) + (threadIdx.x >> 6);
    const int nWaves = gridDim.x * (blockDim.x >> 6);

    for (int tile = wid; tile < nTiles; tile += nWaves) {
        const int e0 = tile * 16;
        const int eA = e0 + m;                     // edge whose metadata this lane owns
        int srcm = 0, dstm = 0;
        float rel = 0.f;
        if (eA < numE) {
            srcm = ei[eA];
            dstm = ei[numE + eA];
            rel  = node_time[srcm] - edge_time[eA];
        }

        // A fragment: ct[k] for edge row m, k = 8g+i.
        f16x8 A;
        #pragma unroll
        for (int i = 0; i < 8; ++i)
            A[i] = (_Float16)__cosf(fmaf(rel, wtr[i], btr[i]));

        f32x4 acc0 = {0.f, 0.f, 0.f, 0.f};
        f32x4 acc1 = {0.f, 0.f, 0.f, 0.f};
        acc0 = __builtin_amdgcn_mfma_f32_16x16x32_f16(A, B0, acc0, 0, 0, 0);
        acc1 = __builtin_amdgcn_mfma_f32_16x16x32_f16(A, B1, acc1, 0, 0, 0);

        #pragma unroll
        for (int r = 0; r < 4; ++r) {
            const int j = g * 4 + r;               // edge-in-tile this reg row holds
            const int e = e0 + j;
            if (e < numE) {
                const int srcr = __shfl(srcm, j);  // lane j owns edge e0+j's metadata
                const int dstr = __shfl(dstm, j);

                const float ef0 = acc0[r] + be0;   // channel m      (head 0)
                const float ef1 = acc1[r] + be1;   // channel 16+m   (head 1)

                const size_t sb = (size_t)srcr * 32;
                const size_t db = (size_t)dstr * 32;
                const float q0 = qb[db + m],      q1 = qb[db + 16 + m];
                const float k0 = kb[sb + m],      k1 = kb[sb + 16 + m];
                const float v0 = vb[sb + m],      v1 = vb[sb + 16 + m];

                float p0 = q0 * (k0 + ef0);
                float p1 = q1 * (k1 + ef1);
                #pragma unroll
                for (int s = 1; s < 16; s <<= 1) { // reduce over the 16 channels
                    p0 += __shfl_xor(p0, s);
                    p1 += __shfl_xor(p1, s);
                }
                const float w0 = __expf(p0 * INV_SQRT_C);
                const float w1 = __expf(p1 * INV_SQRT_C);

                atomicAdd(&agg[db + m],      w0 * (v0 + ef0));
                atomicAdd(&agg[db + 16 + m], w1 * (v1 + ef1));
                if (m < 2) atomicAdd(&den[(size_t)dstr * 2 + m], m ? w1 : w0);
            }
        }
    }
}

// ---------------------------------------------------------------------------
// k4: h2 = agg/denom + skip; out = log_softmax(h2 @ Wout + bout).
// ---------------------------------------------------------------------------
__global__ __launch_bounds__(256) void k4_out(
    const float* __restrict__ agg, const float* __restrict__ den,
    const float* __restrict__ skipb,
    const float* __restrict__ Wout, const float* __restrict__ bout,
    float* __restrict__ out, int n)
{
    __shared__ float sW[64];
    __shared__ float sb[2];
    const int t = threadIdx.x;
    if (t < 64) sW[t] = Wout[t];
    if (t < 2) sb[t] = bout[t];
    __syncthreads();

    const int nid = blockIdx.x * 256 + t;
    if (nid >= n) return;

    const float inv0 = 1.f / (den[(size_t)nid * 2 + 0] + 1e-16f);
    const float inv1 = 1.f / (den[(size_t)nid * 2 + 1] + 1e-16f);
    const float4* ag4 = reinterpret_cast<const float4*>(agg + (size_t)nid * 32);
    const float4* sk4 = reinterpret_cast<const float4*>(skipb + (size_t)nid * 32);

    float o0 = sb[0], o1 = sb[1];
    #pragma unroll
    for (int c4 = 0; c4 < 8; ++c4) {
        float4 a = ag4[c4], s = sk4[c4];
        const float iv = (c4 < 4) ? inv0 : inv1;
        float h;
        h = fmaf(a.x, iv, s.x); o0 = fmaf(h, sW[(c4 * 4 + 0) * 2], o0); o1 = fmaf(h, sW[(c4 * 4 + 0) * 2 + 1], o1);
        h = fmaf(a.y, iv, s.y); o0 = fmaf(h, sW[(c4 * 4 + 1) * 2], o0); o1 = fmaf(h, sW[(c4 * 4 + 1) * 2 + 1], o1);
        h = fmaf(a.z, iv, s.z); o0 = fmaf(h, sW[(c4 * 4 + 2) * 2], o0); o1 = fmaf(h, sW[(c4 * 4 + 2) * 2 + 1], o1);
        h = fmaf(a.w, iv, s.w); o0 = fmaf(h, sW[(c4 * 4 + 3) * 2], o0); o1 = fmaf(h, sW[(c4 * 4 + 3) * 2 + 1], o1);
    }
    const float mm = fmaxf(o0, o1);
    const float lse = mm + __logf(__expf(o0 - mm) + __expf(o1 - mm));
    out[(size_t)nid * 2 + 0] = o0 - lse;
    out[(size_t)nid * 2 + 1] = o1 - lse;
}

// ---------------------------------------------------------------------------
extern "C" void kernel_launch(void* const* d_in, const int* in_sizes, int n_in,
                              void* d_out, int out_size, void* d_ws, size_t ws_size,
                              hipStream_t stream)
{
    const float* x             = (const float*)d_in[0];
    const int*   ei            = (const int*)  d_in[1];
    const float* node_time     = (const float*)d_in[2];
    const float* edge_time     = (const float*)d_in[3];
    const float* node_interval = (const float*)d_in[4];
    const float* node_degree   = (const float*)d_in[5];
    const float* Wt    = (const float*)d_in[6];  const float* bt    = (const float*)d_in[7];
    const float* Wd    = (const float*)d_in[8];  const float* bd    = (const float*)d_in[9];
    const float* Wtf   = (const float*)d_in[10]; const float* btf   = (const float*)d_in[11];
    const float* Wenc  = (const float*)d_in[12]; const float* benc  = (const float*)d_in[13];
    const float* Wx    = (const float*)d_in[14]; const float* bx    = (const float*)d_in[15];
    const float* Wlin  = (const float*)d_in[16]; const float* blin  = (const float*)d_in[17];
    const float* Wcomb = (const float*)d_in[18]; const float* bcomb = (const float*)d_in[19];
    const float* Wq    = (const float*)d_in[20]; const float* bq    = (const float*)d_in[21];
    const float* Wk    = (const float*)d_in[22]; const float* bk    = (const float*)d_in[23];
    const float* Wv    = (const float*)d_in[24]; const float* bv    = (const float*)d_in[25];
    const float* We    = (const float*)d_in[26]; const float* be    = (const float*)d_in[27];
    const float* Wskip = (const float*)d_in[28]; const float* bskip = (const float*)d_in[29];
    const float* Wout  = (const float*)d_in[30]; const float* bout  = (const float*)d_in[31];

    const int n    = in_sizes[2];   // node_time: [N]
    const int numE = in_sizes[3];   // edge_time: [E,1]

    float* ws    = (float*)d_ws;
    float* h1pre = ws;  ws += (size_t)n * 32;
    float* qb    = ws;  ws += (size_t)n * 32;
    float* kb    = ws;  ws += (size_t)n * 32;
    float* vb    = ws;  ws += (size_t)n * 32;
    float* skipb = ws;  ws += (size_t)n * 32;
    float* agg   = ws;  ws += (size_t)n * 32;
    float* den   = ws;  ws += (size_t)n * 2;

    // zero the atomic accumulators (agg and den are contiguous)
    hipMemsetAsync(agg, 0, (size_t)n * 34 * sizeof(float), stream);

    k1_lin<<<(n + 7) / 8, 256, 0, stream>>>(x, Wlin, blin, h1pre, n);

    k2_enc<<<(n + 255) / 256, 256, 0, stream>>>(
        h1pre, node_interval, node_degree,
        Wtf, btf, Wd, bd, Wenc, benc, Wx, bx, Wcomb, bcomb,
        Wq, bq, Wk, bk, Wv, bv, Wskip, bskip,
        qb, kb, vb, skipb, n);

    const int nTiles = (numE + 15) / 16;
    k3_edge<<<2048, 256, 0, stream>>>(
        ei, node_time, edge_time, qb, kb, vb,
        Wt, bt, We, be, agg, den, numE, nTiles);

    k4_out<<<(n + 255) / 256, 256, 0, stream>>>(
        agg, den, skipb, Wout, bout, (float*)d_out, n);
}